// Round 6
// baseline (150.617 us; speedup 1.0000x reference)
//
#include <hip/hip_runtime.h>

// VQ-VAE VectorQuantizer for MI355X — v7: v6 tile + explicit 2-deep d-loop pipeline.
// inputs: d_in[0] = inputs [64, 64, 32, 32] fp32 (NCHW), d_in[1] = emb_w [512, 64] fp32
// output d_out (fp32): [loss(1), quantized NCHW (64*64*32*32), idx (65536)]
//
// Correctness note: the reference computes dist = ||x||^2 + ||e||^2 - 2 x.e in fp32,
// where ||x||^2 ~ 64 quantizes dist to a ~7.6e-6 grid; ~100/65536 points have quantized
// TIES that argmin resolves by first index. We bit-replicate that arithmetic
// (numpy pairwise-sum order for the norms, fp32 rounding sequence for dist: sequential
// fmaf over d=0..63 then fp32((sx+nk) - 2*dot); fmaf(-2,acc,t) == fadd(t,-2*acc) since
// -2*acc is exact) and tie-break by smallest index.
//
// v7 rationale: v6 measured VALU-busy 35us and LDS-busy ~39us but ran 75us -> ~35us of
// neither-pipe stall = exposed lgkmcnt latency: each d-step was {6 ds_read_b128 ->
// wait -> 128 fmaf} and the 2 barrier-synced waves/SIMD phase-lock. Fix: explicit
// double-buffered operand pipeline (xA/eA <-> xB/eB), loads for d+1 issued BEFORE the
// FMA block of d, so the compiler's auto-waitcnt sits after 256cy of FMA. Registers:
// acc 128 (allocator uses AGPR half of the unified file; VALU can source AGPRs on
// CDNA) + 48 operand bufs + 32 runv/runi + misc ~ 223 <= 256 -> still 2 waves/SIMD.
// Also: sxs stored transposed (sxst[j*16+pg]) so dist-phase reads are lane-consecutive
// (v6's stride-16 pattern was 2 banks x 8-way).

#define D_     64
#define HW_    1024
#define N_     65536
#define K_     512
#define M_     256     // points per block
#define XPITCH 288     // x row pitch: 8 chunks * 36 (32 used + 4 pad)
#define EPITCH 256     // e-tile row pitch (one 256-code chunk)
#define NDTOT  (N_ * D_)

// load the 16-point x slice / 8-code e slice for dimension dd into register buffers
#define LOADX(XV, dd) do {                                         \
    const float* xr_ = xcol + (dd) * XPITCH;                       \
    float4 a_ = *(const float4*)(xr_);                             \
    float4 b_ = *(const float4*)(xr_ + 4);                         \
    float4 c_ = *(const float4*)(xr_ + 8);                         \
    float4 d_ = *(const float4*)(xr_ + 12);                        \
    XV[0]=a_.x;  XV[1]=a_.y;  XV[2]=a_.z;  XV[3]=a_.w;             \
    XV[4]=b_.x;  XV[5]=b_.y;  XV[6]=b_.z;  XV[7]=b_.w;             \
    XV[8]=c_.x;  XV[9]=c_.y;  XV[10]=c_.z; XV[11]=c_.w;            \
    XV[12]=d_.x; XV[13]=d_.y; XV[14]=d_.z; XV[15]=d_.w;            \
} while (0)

#define LOADE(EV, dd) do {                                         \
    const float* er_ = ecol + (dd) * EPITCH;                       \
    float4 a_ = *(const float4*)(er_);                             \
    float4 b_ = *(const float4*)(er_ + 4);                         \
    EV[0]=a_.x; EV[1]=a_.y; EV[2]=a_.z; EV[3]=a_.w;                \
    EV[4]=b_.x; EV[5]=b_.y; EV[6]=b_.z; EV[7]=b_.w;                \
} while (0)

#define FMABLK(XV, EV) do {                                        \
    _Pragma("unroll")                                              \
    for (int j = 0; j < 16; ++j)                                   \
        _Pragma("unroll")                                          \
        for (int q = 0; q < 8; ++q)                                \
            acc[j][q] = fmaf(XV[j], EV[q], acc[j][q]);             \
} while (0)

__global__ __launch_bounds__(512, 2) void vq_fused_kernel(const float* __restrict__ inp,
                                                          const float* __restrict__ emb,
                                                          float* __restrict__ out) {
    __shared__ float ldsx[D_ * XPITCH];  // 73728 B: x-tile [d][chunked p]
    __shared__ float ldse[16896];        // 67584 B: e-tile [64][256] / merge mv+mi overlay
    __shared__ float ldsn[K_];           // ||e_k||^2
    __shared__ float sxst[M_];           // ||x_p||^2, TRANSPOSED: [j][pg]
    __shared__ int   fi[M_];             // final index per point
    __shared__ float psum[512];          // loss partials

    const int tid = threadIdx.x;         // 0..511
    const int pg  = tid & 15;            // point-group: 16 points each
    const int kg  = tid >> 4;            // code-group (0..31): 8 codes each
    const int n0  = blockIdx.x * M_;
    const int b   = n0 >> 10;
    const int hw0 = n0 & 1023;
    const float* xbase = inp + b * (D_ * HW_) + hw0;

    // ============ phase A: stage x-tile, ||e||^2, e-chunk0 (all overlapped) ========
#pragma unroll
    for (int i = 0; i < 8; ++i) {
        int q = i * 512 + tid;           // 0..4095 = 64 d * 64 float4-slots
        int d = q >> 6;
        int s = q & 63;                  // float4 slot -> point p = s*4
        float4 v = *(const float4*)(xbase + d * HW_ + s * 4);
        *(float4*)(ldsx + d * XPITCH + (s >> 3) * 36 + (s & 7) * 4) = v;
    }
    // ||e_k||^2: one code per thread, numpy pairwise order.
    {
        const float* e = emb + tid * D_;
        float el[64];
#pragma unroll
        for (int q = 0; q < 16; ++q) {
            float4 v = *(const float4*)(e + q * 4);
            el[4 * q + 0] = v.x; el[4 * q + 1] = v.y;
            el[4 * q + 2] = v.z; el[4 * q + 3] = v.w;
        }
        float r[8];
#pragma unroll
        for (int j = 0; j < 8; ++j) r[j] = __fmul_rn(el[j], el[j]);
#pragma unroll
        for (int i = 1; i < 8; ++i)
#pragma unroll
            for (int j = 0; j < 8; ++j)
                r[j] = __fadd_rn(r[j], __fmul_rn(el[i * 8 + j], el[i * 8 + j]));
        ldsn[tid] = __fadd_rn(__fadd_rn(__fadd_rn(r[0], r[1]), __fadd_rn(r[2], r[3])),
                              __fadd_rn(__fadd_rn(r[4], r[5]), __fadd_rn(r[6], r[7])));
    }
    // e-chunk 0: thread stages code k = tid&255, dim-half dh; transposed to [d][k].
    {
        const int k  = tid & 255;
        const int dh = (tid >> 8) * 32;
        const float* er = emb + k * D_ + dh;
#pragma unroll
        for (int j = 0; j < 8; ++j) {
            float4 v = *(const float4*)(er + j * 4);
            ldse[(dh + j * 4 + 0) * EPITCH + k] = v.x;
            ldse[(dh + j * 4 + 1) * EPITCH + k] = v.y;
            ldse[(dh + j * 4 + 2) * EPITCH + k] = v.z;
            ldse[(dh + j * 4 + 3) * EPITCH + k] = v.w;
        }
    }
    __syncthreads();

    // ---- sxst[j][pg] = ||x_p||^2 (p = pg*16+j), numpy pairwise order (tid<256) ----
    if (tid < M_) {
        const int colb = (tid >> 5) * 36 + (tid & 31);
        float r[8];
#pragma unroll
        for (int j = 0; j < 8; ++j) {
            float v = ldsx[j * XPITCH + colb];
            r[j] = __fmul_rn(v, v);
        }
#pragma unroll
        for (int i = 1; i < 8; ++i)
#pragma unroll
            for (int j = 0; j < 8; ++j) {
                float v = ldsx[(i * 8 + j) * XPITCH + colb];
                r[j] = __fadd_rn(r[j], __fmul_rn(v, v));
            }
        // point index = tid; store transposed: [j = tid&15][pg = tid>>4]
        sxst[(tid & 15) * 16 + (tid >> 4)] =
            __fadd_rn(__fadd_rn(__fadd_rn(r[0], r[1]), __fadd_rn(r[2], r[3])),
                      __fadd_rn(__fadd_rn(r[4], r[5]), __fadd_rn(r[6], r[7])));
    }
    __syncthreads();

    float runv[16];
    int   runi[16];
#pragma unroll
    for (int j = 0; j < 16; ++j) { runv[j] = 3.4e38f; runi[j] = 0; }

    const float* xcol = ldsx + (pg >> 1) * 36 + (pg & 1) * 16;
    const float* ecol = ldse + kg * 8;

    // ============ main: 2 chunks of 256 codes, pipelined d-loop ====================
#pragma unroll 1
    for (int c = 0; c < 2; ++c) {
        if (c) {
            __syncthreads();             // chunk-0 inner reads of ldse done
            const int k  = tid & 255;
            const int dh = (tid >> 8) * 32;
            const float* er = emb + (256 + k) * D_ + dh;
#pragma unroll
            for (int j = 0; j < 8; ++j) {
                float4 v = *(const float4*)(er + j * 4);
                ldse[(dh + j * 4 + 0) * EPITCH + k] = v.x;
                ldse[(dh + j * 4 + 1) * EPITCH + k] = v.y;
                ldse[(dh + j * 4 + 2) * EPITCH + k] = v.z;
                ldse[(dh + j * 4 + 3) * EPITCH + k] = v.w;
            }
            __syncthreads();
        }

        float acc[16][8];
#pragma unroll
        for (int j = 0; j < 16; ++j)
#pragma unroll
            for (int q = 0; q < 8; ++q) acc[j][q] = 0.f;

        // 2-deep software pipeline: loads for d+1 issue BEFORE the FMA block of d,
        // so the waitcnt for buffer B lands after 256cy of FMA on buffer A.
        // d-accumulation ORDER is unchanged (bit-exact chain).
        float xA[16], eA[8], xB[16], eB[8];
        LOADX(xA, 0); LOADE(eA, 0);
#pragma unroll 1
        for (int d = 0; d < 64; d += 2) {
            LOADX(xB, d + 1); LOADE(eB, d + 1);
            FMABLK(xA, eA);
            if (d + 2 < 64) { LOADX(xA, d + 2); LOADE(eA, d + 2); }
            FMABLK(xB, eB);
        }

        // dist = fp32(fp32(sx + n_k) - 2*dot); strict < keeps first (k ascending)
        const int kidx0 = c * 256 + kg * 8;
        float nk[8];
        {
            float4 na = *(const float4*)(ldsn + kidx0);
            float4 nb = *(const float4*)(ldsn + kidx0 + 4);
            nk[0]=na.x; nk[1]=na.y; nk[2]=na.z; nk[3]=na.w;
            nk[4]=nb.x; nk[5]=nb.y; nk[6]=nb.z; nk[7]=nb.w;
        }
#pragma unroll
        for (int j = 0; j < 16; ++j) {
            const float sx = sxst[j * 16 + pg];   // lane-consecutive, conflict-free
#pragma unroll
            for (int q = 0; q < 8; ++q) {
                float t = __fadd_rn(sx, nk[q]);
                float v = fmaf(-2.0f, acc[j][q], t);   // == fadd(t, -2*acc), exact prod
                if (v < runv[j]) { runv[j] = v; runi[j] = kidx0 + q; }
            }
        }
    }

    // ============ cross-lane argmin merge (32 candidates/point) ====================
    __syncthreads();                     // inner reads of ldse done -> overlay mv/mi
    float* mv = ldse;                    // [256][33] padded
    int*   mi = (int*)(ldse + 256 * 33);
#pragma unroll
    for (int j = 0; j < 16; ++j) {
        int p = pg * 16 + j;
        mv[p * 33 + kg] = runv[j];
        mi[p * 33 + kg] = runi[j];
    }
    __syncthreads();
    if (tid < M_) {
        float bv = 3.4e38f; int bi = 0x7fffffff;
#pragma unroll
        for (int g = 0; g < 32; ++g) {
            float v  = mv[tid * 33 + g];
            int   ii = mi[tid * 33 + g];
            if (v < bv || (v == bv && ii < bi)) { bv = v; bi = ii; }
        }
        fi[tid] = bi;
        out[1 + NDTOT + n0 + tid] = (float)bi;   // idx as float
    }
    __syncthreads();

    // ============ epilogue: quantized NCHW + loss ==================================
    {
        const int p  = tid & 255;        // point
        const int dh = (tid >> 8) * 32;  // dim half
        const float* er2 = emb + fi[p] * D_ + dh;
        float ev2[32];
#pragma unroll
        for (int q = 0; q < 8; ++q) {
            float4 v = *(const float4*)(er2 + 4 * q);
            ev2[4 * q + 0] = v.x; ev2[4 * q + 1] = v.y;
            ev2[4 * q + 2] = v.z; ev2[4 * q + 3] = v.w;
        }
        float* ob = out + 1 + b * (D_ * HW_) + hw0 + p;
        const int colb = (p >> 5) * 36 + (p & 31);
        float local = 0.f;
#pragma unroll
        for (int dd = 0; dd < 32; ++dd) {
            float xv = ldsx[(dh + dd) * XPITCH + colb];
            float df = ev2[dd] - xv;
            local = fmaf(df, df, local);
            ob[(dh + dd) * HW_] = ev2[dd];   // 256 consecutive floats per instr
        }
        psum[tid] = local;
    }
    __syncthreads();
    if (tid < 64) {
        float s = 0.f;
#pragma unroll
        for (int g = 0; g < 8; ++g) s += psum[tid + 64 * g];
#pragma unroll
        for (int off = 32; off > 0; off >>= 1)
            s += __shfl_down(s, off, 64);
        if (tid == 0)
            atomicAdd(out, s * (1.25f / (float)NDTOT));   // loss = 1.25*mean((q-x)^2)
    }
}

extern "C" void kernel_launch(void* const* d_in, const int* in_sizes, int n_in,
                              void* d_out, int out_size, void* d_ws, size_t ws_size,
                              hipStream_t stream) {
    const float* inp = (const float*)d_in[0];
    const float* emb = (const float*)d_in[1];
    float* out = (float*)d_out;
    (void)d_ws; (void)ws_size;

    hipMemsetAsync(d_out, 0, sizeof(float), stream);   // loss accumulator
    vq_fused_kernel<<<256, 512, 0, stream>>>(inp, emb, out);
}